// Round 5
// baseline (437.990 us; speedup 1.0000x reference)
//
#include <hip/hip_runtime.h>
#include <hip/hip_cooperative_groups.h>
#include <math.h>

namespace cg = cooperative_groups;

#define NN 2708
#define IC 1433
#define OC 128
#define NV (NN / 4)          // 677 float4/int4 per row (exact)
#define NNOC ((size_t)NN * OC)
#define NW 85                // ceil(NN/32) bitmap words per row
#define NMERGE 339           // ceil((NNOC/4)/256)

// LDS union across phases (max 23040 B -> 6 blocks/CU by LDS)
struct __align__(16) SMem {
  union {
    float tile[32][33];      // P0: transpose tile / wvec a1s,a2s
    char bsm[23040];         // P1: xw w1s/w2s (22928) or gemm Xs(32x36)+Ws(32x132)
    struct {                 // P4: softmax+gather
      float vf[NN];
      short js[NN];
      float hpart[4][128];
      unsigned bmr[NW];
      double redd[4];
      float redf[4];
      int cntS;
    } e;
  } u;
};

// Single fused pipeline. phase = -1: cooperative, all phases with grid syncs.
// phase = k >= 0: run only phase k (fallback path; kernel boundaries provide sync).
__global__ __launch_bounds__(256) void fused(
    const int* __restrict__ A, unsigned* __restrict__ bm,
    const float* __restrict__ W, float* __restrict__ Wt,
    const float* __restrict__ a1v, const float* __restrict__ a2v,
    double* __restrict__ w1, double* __restrict__ w2,
    const float* __restrict__ X,
    double* __restrict__ k1, double* __restrict__ k2,
    float* __restrict__ Kp, float* __restrict__ Kf,
    const float* __restrict__ U, const float* __restrict__ lmbd,
    double* __restrict__ u1, double* __restrict__ sC,
    double* __restrict__ p, double* __restrict__ q,
    float* __restrict__ H,
    int nsplit, int chunk, int phase) {
  __shared__ SMem sm;
  const int t = threadIdx.x;
  const bool coop = (phase < 0);

  // ================= P0: transposeW (180) | wvec (6) =================
  if (coop || phase == 0) {
    for (int tk = blockIdx.x; tk < 186; tk += gridDim.x) {
      if (tk < 180) {
        const int k0 = (tk % 45) * 32, o0 = (tk / 45) * 32;
#pragma unroll
        for (int it = 0; it < 4; it++) {
          int ro = (t >> 5) + it * 8;
          int k  = k0 + (t & 31);
          sm.u.tile[ro][t & 31] = (k < IC) ? W[(size_t)(o0 + ro) * IC + k] : 0.f;
        }
        __syncthreads();
#pragma unroll
        for (int it = 0; it < 4; it++) {
          int rk = (t >> 5) + it * 8;
          int k  = k0 + rk;
          if (k < IC) Wt[(size_t)k * OC + o0 + (t & 31)] = sm.u.tile[t & 31][rk];
        }
      } else {
        float* a1s = &sm.u.tile[0][0];
        float* a2s = a1s + 128;
        if (t < 128) { a1s[t] = a1v[t]; a2s[t] = a2v[t]; }
        __syncthreads();
        int c = (tk - 180) * 256 + t;
        if (c < IC) {
          const float* Wc = W + c;
          double s1 = 0.0, s2 = 0.0;
#pragma unroll 4
          for (int o = 0; o < OC; o++) {
            double wv = (double)Wc[(size_t)o * IC];
            s1 = fma(wv, (double)a1s[o], s1);
            s2 = fma(wv, (double)a2s[o], s2);
          }
          w1[c] = s1; w2[c] = s2;
        }
      }
      __syncthreads();
    }
  }
  if (coop) cg::this_grid().sync();

  // ================= P1: xw (677) | gemmK (85*ns) | bitmap+zero (900) =================
  if (coop || phase == 1) {
    const int ngm = 85 * nsplit;
    const int ntask = 677 + ngm + 900;
    for (int tk = blockIdx.x; tk < ntask; tk += gridDim.x) {
      if (tk < 677) {
        // ---- xw: k1 = X@w1, k2 = X@w2 (fp64), one wave per row ----
        double* w1s = (double*)sm.u.bsm;
        double* w2s = w1s + IC;
        for (int c = t; c < IC; c += 256) { w1s[c] = w1[c]; w2s[c] = w2[c]; }
        __syncthreads();
        const int wave = t >> 6, lane = t & 63;
        const int i = tk * 4 + wave;
        const float* Xi = X + (size_t)i * IC;
        double s1 = 0.0, s2 = 0.0;
        for (int c = lane; c < IC; c += 64) {
          double x = (double)Xi[c];
          s1 = fma(x, w1s[c], s1);
          s2 = fma(x, w2s[c], s2);
        }
        for (int o = 32; o; o >>= 1) { s1 += __shfl_down(s1, o, 64); s2 += __shfl_down(s2, o, 64); }
        if (lane == 0) { k1[i] = s1; k2[i] = s2; }
      } else if (tk < 677 + ngm) {
        // ---- gemmK: K partials = X @ Wt over k-chunk (fp32) ----
        float (*Xs)[36]  = (float (*)[36])sm.u.bsm;
        float (*Ws)[132] = (float (*)[132])(sm.u.bsm + 32 * 36 * 4);
        const int bb = tk - 677;
        const int bx = bb % 85, by = bb / 85;
        const int rb = bx * 32;
        const int ks = by * chunk;
        const int ke = min(IC, ks + chunk);
        float* __restrict__ Ko = Kp + (size_t)by * NNOC;
        const int row0 = (t >> 5) * 4;
        const int col4 = (t & 31) * 4;
        float acc[4][4];
#pragma unroll
        for (int r = 0; r < 4; r++)
#pragma unroll
          for (int c = 0; c < 4; c++) acc[r][c] = 0.f;

        for (int kb = ks; kb < ke; kb += 32) {
#pragma unroll
          for (int it = 0; it < 4; it++) {
            int idx = t + it * 256;
            int r = idx >> 5, c = idx & 31;
            int gr = rb + r, gc = kb + c;
            Xs[r][c] = (gr < NN && gc < ke) ? X[(size_t)gr * IC + gc] : 0.f;
          }
#pragma unroll
          for (int it = 0; it < 4; it++) {
            int idx4 = t + it * 256;
            int k = idx4 >> 5, cg2 = (idx4 & 31) * 4;
            int gk = kb + k;
            float4 v = make_float4(0.f, 0.f, 0.f, 0.f);
            if (gk < ke) v = *reinterpret_cast<const float4*>(&Wt[(size_t)gk * OC + cg2]);
            *reinterpret_cast<float4*>(&Ws[k][cg2]) = v;
          }
          __syncthreads();
#pragma unroll
          for (int g = 0; g < 8; g++) {
            float xr[4][4];
#pragma unroll
            for (int r = 0; r < 4; r++)
              *reinterpret_cast<float4*>(xr[r]) = *reinterpret_cast<const float4*>(&Xs[row0 + r][g * 4]);
#pragma unroll
            for (int j = 0; j < 4; j++) {
              const float4 w4 = *reinterpret_cast<const float4*>(&Ws[g * 4 + j][col4]);
#pragma unroll
              for (int r = 0; r < 4; r++) {
                acc[r][0] = fmaf(xr[r][j], w4.x, acc[r][0]);
                acc[r][1] = fmaf(xr[r][j], w4.y, acc[r][1]);
                acc[r][2] = fmaf(xr[r][j], w4.z, acc[r][2]);
                acc[r][3] = fmaf(xr[r][j], w4.w, acc[r][3]);
              }
            }
          }
          __syncthreads();
        }
#pragma unroll
        for (int r = 0; r < 4; r++) {
          int gr = rb + row0 + r;
          if (gr < NN) {
            float4 v = make_float4(acc[r][0], acc[r][1], acc[r][2], acc[r][3]);
            *reinterpret_cast<float4*>(&Ko[(size_t)gr * OC + col4]) = v;
          }
        }
      } else {
        // ---- bitmap of A + zero u1/sC (u1, sC contiguous) ----
        const int b = tk - 677 - ngm;
        int gid = b * 256 + t;
        if (gid < 2 * NN) u1[gid] = 0.0;
        const int total = NN * NW;
        if (gid < total) {
          int i = gid / NW, w = gid - i * NW;
          const int* Ar = A + (size_t)i * NN + w * 32;
          unsigned word = 0;
          if (w < NW - 1) {
            const int4* a4 = (const int4*)Ar;
#pragma unroll
            for (int uu = 0; uu < 8; uu++) {
              int4 a = a4[uu];
              word |= (a.x != 0 ? 1u : 0u) << (4 * uu);
              word |= (a.y != 0 ? 1u : 0u) << (4 * uu + 1);
              word |= (a.z != 0 ? 1u : 0u) << (4 * uu + 2);
              word |= (a.w != 0 ? 1u : 0u) << (4 * uu + 3);
            }
          } else {
            const int nbits = NN - w * 32;
            for (int bb2 = 0; bb2 < nbits; bb2++) word |= (Ar[bb2] != 0 ? 1u : 0u) << bb2;
          }
          bm[(size_t)i * NW + w] = word;
        }
      }
      __syncthreads();
    }
  }
  if (coop) cg::this_grid().sync();

  // ================= P2: ut_reduce (255) | mergeK (339 if ns>1) =================
  if (coop || phase == 2) {
    const int ntask = 255 + (nsplit > 1 ? NMERGE : 0);
    for (int tk = blockIdx.x; tk < ntask; tk += gridDim.x) {
      if (tk < 255) {
        const int slab = tk / 3, ch = tk - slab * 3;
        const int c4 = ch * 256 + t;
        if (c4 < NV) {
          const float4* U4 = (const float4*)U;
          const int r0 = slab * 32;
          const int r1 = min(NN, r0 + 32);
          double au0 = 0, au1_ = 0, au2 = 0, au3 = 0, as0 = 0, as1 = 0, as2 = 0, as3 = 0;
#pragma unroll 4
          for (int r = r0; r < r1; r++) {
            float4 uu = U4[(size_t)r * NV + c4];
            double kr = k1[r];
            au0 = fma((double)uu.x, kr, au0); au1_ = fma((double)uu.y, kr, au1_);
            au2 = fma((double)uu.z, kr, au2); au3 = fma((double)uu.w, kr, au3);
            as0 += (double)uu.x; as1 += (double)uu.y; as2 += (double)uu.z; as3 += (double)uu.w;
          }
          int c = c4 * 4;
          atomicAdd(&u1[c + 0], au0); atomicAdd(&u1[c + 1], au1_);
          atomicAdd(&u1[c + 2], au2); atomicAdd(&u1[c + 3], au3);
          atomicAdd(&sC[c + 0], as0); atomicAdd(&sC[c + 1], as1);
          atomicAdd(&sC[c + 2], as2); atomicAdd(&sC[c + 3], as3);
        }
      } else {
        size_t i = (size_t)(tk - 255) * 256 + t;
        const size_t n4 = NNOC / 4;
        if (i < n4) {
          const float4* Kp4 = (const float4*)Kp;
          float4 sv;
          if (nsplit == 16) {
            float4 v[16];
#pragma unroll
            for (int pp = 0; pp < 16; pp++) v[pp] = Kp4[(size_t)pp * n4 + i];
            sv = v[0];
#pragma unroll
            for (int pp = 1; pp < 16; pp++) { sv.x += v[pp].x; sv.y += v[pp].y; sv.z += v[pp].z; sv.w += v[pp].w; }
          } else if (nsplit == 8) {
            float4 v[8];
#pragma unroll
            for (int pp = 0; pp < 8; pp++) v[pp] = Kp4[(size_t)pp * n4 + i];
            sv = v[0];
#pragma unroll
            for (int pp = 1; pp < 8; pp++) { sv.x += v[pp].x; sv.y += v[pp].y; sv.z += v[pp].z; sv.w += v[pp].w; }
          } else if (nsplit == 4) {
            float4 v[4];
#pragma unroll
            for (int pp = 0; pp < 4; pp++) v[pp] = Kp4[(size_t)pp * n4 + i];
            sv = v[0];
#pragma unroll
            for (int pp = 1; pp < 4; pp++) { sv.x += v[pp].x; sv.y += v[pp].y; sv.z += v[pp].z; sv.w += v[pp].w; }
          } else {
            sv = Kp4[i];
            for (int pp = 1; pp < nsplit; pp++) {
              float4 v = Kp4[(size_t)pp * n4 + i];
              sv.x += v.x; sv.y += v.y; sv.z += v.z; sv.w += v.w;
            }
          }
          ((float4*)Kf)[i] = sv;
        }
      }
    }
  }
  if (coop) cg::this_grid().sync();

  // ================= P3: uv (677): p = U@(lmbd*u1), q = U@(lmbd*s) =================
  if (coop || phase == 3) {
    const float4* U4 = (const float4*)U;
    const float4* L4 = (const float4*)lmbd;
    const double2* u1d = (const double2*)u1;
    const double2* sd  = (const double2*)sC;
    for (int tk = blockIdx.x; tk < 677; tk += gridDim.x) {
      const int wave = t >> 6, lane = t & 63;
      const int r = tk * 4 + wave;
      const float4* Ur = U4 + (size_t)r * NV;
      double ap = 0.0, aq = 0.0;
      for (int c4 = lane; c4 < NV; c4 += 64) {
        float4 uu = Ur[c4];
        float4 lm = L4[c4];
        double2 ua = u1d[c4 * 2], ub = u1d[c4 * 2 + 1];
        double2 sa = sd[c4 * 2],  sb = sd[c4 * 2 + 1];
        ap = fma((double)uu.x, (double)lm.x * ua.x, ap);
        ap = fma((double)uu.y, (double)lm.y * ua.y, ap);
        ap = fma((double)uu.z, (double)lm.z * ub.x, ap);
        ap = fma((double)uu.w, (double)lm.w * ub.y, ap);
        aq = fma((double)uu.x, (double)lm.x * sa.x, aq);
        aq = fma((double)uu.y, (double)lm.y * sa.y, aq);
        aq = fma((double)uu.z, (double)lm.z * sb.x, aq);
        aq = fma((double)uu.w, (double)lm.w * sb.y, aq);
      }
      for (int o = 32; o; o >>= 1) { ap += __shfl_down(ap, o, 64); aq += __shfl_down(aq, o, 64); }
      if (lane == 0) { p[r] = ap; q[r] = aq; }
    }
  }
  if (coop) cg::this_grid().sync();

  // ================= P4: two-pass masked softmax + deep-ILP gather (2708 rows) =================
  if (coop || phase == 4) {
    float* vf = sm.u.e.vf;
    short* js = sm.u.e.js;
    float (*hpart)[128] = sm.u.e.hpart;
    unsigned* bmr = sm.u.e.bmr;
    double* redd = sm.u.e.redd;
    float* redf = sm.u.e.redf;
    const int wv = t >> 6, lane = t & 63;
    const unsigned long long ltmask = (1ull << lane) - 1ull;

    for (int i = blockIdx.x; i < NN; i += gridDim.x) {
      const double pi = p[i], qi = q[i];
      if (t < NW) bmr[t] = bm[(size_t)i * NW + t];
      if (t == 0) sm.u.e.cntS = 0;
      __syncthreads();

      // pass 1: exact neighbor max of |v|
      double m = -1e300;
      for (int j = t; j < NN; j += 256) {
        if ((bmr[j >> 5] >> (j & 31)) & 1u) {
          double v = fma(qi, k2[j], pi);
          m = fmax(m, fabs(v));
        }
      }
      for (int o = 32; o; o >>= 1) m = fmax(m, __shfl_xor(m, o, 64));
      if (lane == 0) redd[wv] = m;
      __syncthreads();
      m = fmax(fmax(redd[0], redd[1]), fmax(redd[2], redd[3]));

      // pass 2: weights + wave-aggregated compaction
      const double thr = m - 21.0;   // exp(-21) ~ 7.6e-10 relative mass cut
      float sw = 0.f;
      for (int j = t; j < NN; j += 256) {
        bool keep = false;
        double av = 0.0;
        if ((bmr[j >> 5] >> (j & 31)) & 1u) {
          av = fabs(fma(qi, k2[j], pi));
          keep = (av > thr);
        }
        unsigned long long mask = __ballot(keep);
        if (mask) {
          int src = __ffsll(mask) - 1;
          int basew = 0;
          if (lane == src) basew = atomicAdd(&sm.u.e.cntS, __popcll(mask));
          basew = __shfl(basew, src, 64);
          if (keep) {
            int pos = basew + __popcll(mask & ltmask);
            float w = __expf((float)(av - m));
            js[pos] = (short)j;
            vf[pos] = w;
            sw += w;
          }
        }
      }
      for (int o = 32; o; o >>= 1) sw += __shfl_xor(sw, o, 64);
      if (lane == 0) redf[wv] = sw;
      __syncthreads();
      const float sumw = (redf[0] + redf[1]) + (redf[2] + redf[3]);
      const int nlist = sm.u.e.cntS;

      // gather: 8 candidates per batch (stride 4 per wave), 16 loads in flight
      const int ch = t & 63, g = t >> 6;
      float a0 = 0.f, a1 = 0.f;
      int c = g;
      for (; c + 28 < nlist; c += 32) {
        float wr[8]; int jr[8];
#pragma unroll
        for (int uu = 0; uu < 8; uu++) { wr[uu] = vf[c + 4 * uu]; jr[uu] = js[c + 4 * uu]; }
        float kl[8], kh[8];
#pragma unroll
        for (int uu = 0; uu < 8; uu++) {
          const float* Kr = Kf + (size_t)jr[uu] * OC;
          kl[uu] = Kr[ch]; kh[uu] = Kr[64 + ch];
        }
#pragma unroll
        for (int uu = 0; uu < 8; uu++) { a0 = fmaf(wr[uu], kl[uu], a0); a1 = fmaf(wr[uu], kh[uu], a1); }
      }
      for (; c < nlist; c += 4) {
        float w = vf[c];
        const float* Kr = Kf + (size_t)js[c] * OC;
        a0 = fmaf(w, Kr[ch], a0);
        a1 = fmaf(w, Kr[64 + ch], a1);
      }
      hpart[g][ch] = a0;
      hpart[g][64 + ch] = a1;
      __syncthreads();
      if (t < 128) {
        float hv = (hpart[0][t] + hpart[1][t]) + (hpart[2][t] + hpart[3][t]);
        H[(size_t)i * OC + t] = hv / sumw;
      }
      __syncthreads();   // LDS reuse before next row
    }
  }
}

extern "C" void kernel_launch(void* const* d_in, const int* in_sizes, int n_in,
                              void* d_out, int out_size, void* d_ws, size_t ws_size,
                              hipStream_t stream) {
  const int*   A    = (const int*)d_in[1];
  const float* X    = (const float*)d_in[0];
  const float* U    = (const float*)d_in[2];
  const float* W    = (const float*)d_in[3];
  const float* a1   = (const float*)d_in[4];
  const float* a2   = (const float*)d_in[5];
  const float* lmbd = (const float*)d_in[6];
  float* H = (float*)d_out;

  const size_t wt_bytes  = (size_t)IC * OC * 4;
  const size_t bm_bytes  = (size_t)NN * NW * 4;
  const size_t dbl_bytes = (size_t)(6 * NN + 2 * IC) * 8;

  // split-K cascade by workspace size
  const int splits[5] = {16, 8, 4, 2, 1};
  int nsplit = 1;
  for (int ci = 0; ci < 5; ci++) {
    int ns = splits[ci];
    size_t need = (size_t)(ns > 1 ? ns + 1 : 1) * NNOC * 4 + wt_bytes + dbl_bytes +
                  bm_bytes + 1024;
    if (need <= ws_size) { nsplit = ns; break; }
  }

  char* base = (char*)d_ws;
  float* Kp = (float*)base;
  float* Kf = (nsplit > 1) ? (float*)(base + (size_t)nsplit * NNOC * 4) : Kp;
  size_t off = (size_t)(nsplit > 1 ? nsplit + 1 : 1) * NNOC * 4;
  float* Wt = (float*)(base + off);            off += wt_bytes;
  double* dbl = (double*)(base + off);         off += dbl_bytes;
  double* k1  = dbl;
  double* k2  = k1 + NN;
  double* u1  = k2 + NN;
  double* sC  = u1 + NN;
  double* p   = sC + NN;
  double* q   = p  + NN;
  double* w1  = q  + NN;
  double* w2  = w1 + IC;
  unsigned* bm = (unsigned*)(base + off);      off += bm_bytes;

  int chunk = (IC + nsplit - 1) / nsplit;

  // cooperative grid size: exact co-residency from occupancy query (cached)
  static int nblk_cache = -1;
  if (nblk_cache < 0) {
    int occ = 0;
    if (hipOccupancyMaxActiveBlocksPerMultiprocessor(&occ, fused, 256, 0) != hipSuccess || occ <= 0)
      occ = 2;
    int ncu = 256;
    hipDeviceProp_t prop;
    if (hipGetDeviceProperties(&prop, 0) == hipSuccess && prop.multiProcessorCount > 0)
      ncu = prop.multiProcessorCount;
    nblk_cache = occ * ncu;
  }
  int ntask_max = 677 + 85 * nsplit + 900;     // P1 (P4 = 2708 loops fine)
  if (ntask_max < NN) ntask_max = NN;
  int NBLK = nblk_cache < ntask_max ? nblk_cache : ntask_max;

  int phase = -1;
  void* args[] = {(void*)&A, (void*)&bm, (void*)&W, (void*)&Wt, (void*)&a1, (void*)&a2,
                  (void*)&w1, (void*)&w2, (void*)&X, (void*)&k1, (void*)&k2,
                  (void*)&Kp, (void*)&Kf, (void*)&U, (void*)&lmbd, (void*)&u1, (void*)&sC,
                  (void*)&p, (void*)&q, (void*)&H, (void*)&nsplit, (void*)&chunk, (void*)&phase};
  hipError_t err = hipLaunchCooperativeKernel(fused, dim3(NBLK), dim3(256), args, 0, stream);
  if (err != hipSuccess) {
    // fallback: same kernel, 5 sequential phase launches (kernel boundaries = sync)
    fused<<<186, 256, 0, stream>>>(A, bm, W, Wt, a1, a2, w1, w2, X, k1, k2, Kp, Kf,
                                   U, lmbd, u1, sC, p, q, H, nsplit, chunk, 0);
    fused<<<677 + 85 * nsplit + 900, 256, 0, stream>>>(A, bm, W, Wt, a1, a2, w1, w2, X, k1, k2, Kp, Kf,
                                                       U, lmbd, u1, sC, p, q, H, nsplit, chunk, 1);
    fused<<<255 + (nsplit > 1 ? NMERGE : 0), 256, 0, stream>>>(A, bm, W, Wt, a1, a2, w1, w2, X, k1, k2, Kp, Kf,
                                                               U, lmbd, u1, sC, p, q, H, nsplit, chunk, 2);
    fused<<<677, 256, 0, stream>>>(A, bm, W, Wt, a1, a2, w1, w2, X, k1, k2, Kp, Kf,
                                   U, lmbd, u1, sC, p, q, H, nsplit, chunk, 3);
    fused<<<NN, 256, 0, stream>>>(A, bm, W, Wt, a1, a2, w1, w2, X, k1, k2, Kp, Kf,
                                  U, lmbd, u1, sC, p, q, H, nsplit, chunk, 4);
  }
}

// Round 6
// 213.147 us; speedup vs baseline: 2.0549x; 2.0549x over previous
//
#include <hip/hip_runtime.h>
#include <math.h>

#define NN 2708
#define IC 1433
#define OC 128
#define NV (NN / 4)          // 677 float4/int4 per row (exact)
#define NNOC ((size_t)NN * OC)
#define NW 85                // ceil(NN/32) bitmap words per row

// ============ kernel A: prep = { bitmapA+zero | transposeW | wvec direct } ============
// blocks [0,900): bitmap of A + zero u1/sC
// blocks [900,1080): Wt[k][o] = W[o][k]
// blocks [1080,1086): w1 = W^T a1, w2 = W^T a2 (fp64 column reduction, W read directly)
__global__ __launch_bounds__(256) void prep(const int* __restrict__ A, unsigned* __restrict__ bm,
                                            double* __restrict__ zd, int nzd,
                                            const float* __restrict__ W, float* __restrict__ Wt,
                                            const float* __restrict__ a1, const float* __restrict__ a2,
                                            double* __restrict__ w1, double* __restrict__ w2) {
  __shared__ float tile[32][33];   // transpose tile; also aliased by wvec branch (needs 256 floats)
  const int b = blockIdx.x, t = threadIdx.x;
  if (b < 900) {
    int gid = b * 256 + t;
    if (gid < nzd) zd[gid] = 0.0;
    const int total = NN * NW;
    if (gid >= total) return;
    int i = gid / NW, w = gid - i * NW;
    const int* Ar = A + (size_t)i * NN + w * 32;
    unsigned word = 0;
    if (w < NW - 1) {
      const int4* a4 = (const int4*)Ar;
#pragma unroll
      for (int u = 0; u < 8; u++) {
        int4 a = a4[u];
        word |= (a.x != 0 ? 1u : 0u) << (4 * u);
        word |= (a.y != 0 ? 1u : 0u) << (4 * u + 1);
        word |= (a.z != 0 ? 1u : 0u) << (4 * u + 2);
        word |= (a.w != 0 ? 1u : 0u) << (4 * u + 3);
      }
    } else {
      const int nbits = NN - w * 32;
      for (int bb = 0; bb < nbits; bb++) word |= (Ar[bb] != 0 ? 1u : 0u) << bb;
    }
    bm[(size_t)i * NW + w] = word;
  } else if (b < 1080) {
    const int idx = b - 900;
    const int k0 = (idx % 45) * 32, o0 = (idx / 45) * 32;
#pragma unroll
    for (int it = 0; it < 4; it++) {
      int ro = (t >> 5) + it * 8;
      int k  = k0 + (t & 31);
      tile[ro][t & 31] = (k < IC) ? W[(size_t)(o0 + ro) * IC + k] : 0.f;
    }
    __syncthreads();
#pragma unroll
    for (int it = 0; it < 4; it++) {
      int rk = (t >> 5) + it * 8;
      int k  = k0 + rk;
      if (k < IC) Wt[(size_t)k * OC + o0 + (t & 31)] = tile[t & 31][rk];
    }
  } else {
    float* a1s = &tile[0][0];
    float* a2s = a1s + 128;
    if (t < 128) { a1s[t] = a1[t]; a2s[t] = a2[t]; }
    __syncthreads();
    int c = (b - 1080) * 256 + t;
    if (c < IC) {
      const float* Wc = W + c;
      double s1 = 0.0, s2 = 0.0;
#pragma unroll 4
      for (int o = 0; o < OC; o++) {
        double w = (double)Wc[(size_t)o * IC];
        s1 = fma(w, (double)a1s[o], s1);
        s2 = fma(w, (double)a2s[o], s2);
      }
      w1[c] = s1; w2[c] = s2;
    }
  }
}

// ============ kernel B: { xw | gemmK } ============
// blocks [0,677): k1 = X@w1, k2 = X@w2 (fp64), one wave per row; w1/w2 read direct (L2-hot)
// blocks [677, 677+85*nsplit): K partials = X @ Wt over k-chunk (fp32)
__global__ __launch_bounds__(256) void xw_gemm(const float* __restrict__ X,
                                               const double* __restrict__ w1, const double* __restrict__ w2,
                                               double* __restrict__ k1, double* __restrict__ k2,
                                               const float* __restrict__ Wt, float* __restrict__ Kp,
                                               int chunk) {
  __shared__ __align__(16) char smem[21504];   // gemm: Xs(32x36)+Ws(32x132) = 21504
  const int b = blockIdx.x, t = threadIdx.x;
  if (b < NN / 4) {
    const int wave = t >> 6, lane = t & 63;
    const int i = b * 4 + wave;
    const float* Xi = X + (size_t)i * IC;
    double s1 = 0.0, s2 = 0.0;
    for (int c = lane; c < IC; c += 64) {
      double x = (double)Xi[c];
      s1 = fma(x, w1[c], s1);
      s2 = fma(x, w2[c], s2);
    }
    for (int o = 32; o; o >>= 1) { s1 += __shfl_down(s1, o, 64); s2 += __shfl_down(s2, o, 64); }
    if (lane == 0) { k1[i] = s1; k2[i] = s2; }
  } else {
    float (*Xs)[36]  = (float (*)[36])smem;
    float (*Ws)[132] = (float (*)[132])(smem + 32 * 36 * 4);
    const int bb = b - NN / 4;
    const int bx = bb % 85, by = bb / 85;
    const int rb = bx * 32;
    const int ks = by * chunk;
    const int ke = min(IC, ks + chunk);
    float* __restrict__ Ko = Kp + (size_t)by * NNOC;
    const int row0 = (t >> 5) * 4;
    const int col4 = (t & 31) * 4;
    float acc[4][4];
#pragma unroll
    for (int r = 0; r < 4; r++)
#pragma unroll
      for (int c = 0; c < 4; c++) acc[r][c] = 0.f;

    for (int kb = ks; kb < ke; kb += 32) {
#pragma unroll
      for (int it = 0; it < 4; it++) {
        int idx = t + it * 256;
        int r = idx >> 5, c = idx & 31;
        int gr = rb + r, gc = kb + c;
        Xs[r][c] = (gr < NN && gc < ke) ? X[(size_t)gr * IC + gc] : 0.f;
      }
#pragma unroll
      for (int it = 0; it < 4; it++) {
        int idx4 = t + it * 256;
        int k = idx4 >> 5, cg = (idx4 & 31) * 4;
        int gk = kb + k;
        float4 v = make_float4(0.f, 0.f, 0.f, 0.f);
        if (gk < ke) v = *reinterpret_cast<const float4*>(&Wt[(size_t)gk * OC + cg]);
        *reinterpret_cast<float4*>(&Ws[k][cg]) = v;
      }
      __syncthreads();
#pragma unroll
      for (int g = 0; g < 8; g++) {
        float xr[4][4];
#pragma unroll
        for (int r = 0; r < 4; r++)
          *reinterpret_cast<float4*>(xr[r]) = *reinterpret_cast<const float4*>(&Xs[row0 + r][g * 4]);
#pragma unroll
        for (int j = 0; j < 4; j++) {
          const float4 w4 = *reinterpret_cast<const float4*>(&Ws[g * 4 + j][col4]);
#pragma unroll
          for (int r = 0; r < 4; r++) {
            acc[r][0] = fmaf(xr[r][j], w4.x, acc[r][0]);
            acc[r][1] = fmaf(xr[r][j], w4.y, acc[r][1]);
            acc[r][2] = fmaf(xr[r][j], w4.z, acc[r][2]);
            acc[r][3] = fmaf(xr[r][j], w4.w, acc[r][3]);
          }
        }
      }
      __syncthreads();
    }
#pragma unroll
    for (int r = 0; r < 4; r++) {
      int gr = rb + row0 + r;
      if (gr < NN) {
        float4 v = make_float4(acc[r][0], acc[r][1], acc[r][2], acc[r][3]);
        *reinterpret_cast<float4*>(&Ko[(size_t)gr * OC + col4]) = v;
      }
    }
  }
}

// ============ kernel C: { ut_reduce | mergeK }, 256-thread blocks ============
// blocks [0,255): u1 = U^T@k1, s = U^T@1 (fp64, atomics); slab=b/3 (32 rows), chunk=b%3 (256 cols4)
// blocks [255, 255+339) (only if nsplit>1): merge split-K partials, 1 float4/thread, 16 loads in flight
__global__ __launch_bounds__(256) void mid(const float4* __restrict__ U4, const double* __restrict__ k1,
                                           double* __restrict__ u1, double* __restrict__ s,
                                           const float4* __restrict__ Kp4, float4* __restrict__ Kf4,
                                           int nsplit) {
  const int b = blockIdx.x, t = threadIdx.x;
  if (b < 255) {
    const int slab = b / 3, chunk = b - slab * 3;
    const int c4 = chunk * 256 + t;
    if (c4 >= NV) return;
    const int r0 = slab * 32;
    const int r1 = min(NN, r0 + 32);
    double au0 = 0, au1_ = 0, au2 = 0, au3 = 0, as0 = 0, as1 = 0, as2 = 0, as3 = 0;
#pragma unroll 4
    for (int r = r0; r < r1; r++) {
      float4 u = U4[(size_t)r * NV + c4];
      double kr = k1[r];
      au0 = fma((double)u.x, kr, au0); au1_ = fma((double)u.y, kr, au1_);
      au2 = fma((double)u.z, kr, au2); au3 = fma((double)u.w, kr, au3);
      as0 += (double)u.x; as1 += (double)u.y; as2 += (double)u.z; as3 += (double)u.w;
    }
    int c = c4 * 4;
    atomicAdd(&u1[c + 0], au0); atomicAdd(&u1[c + 1], au1_);
    atomicAdd(&u1[c + 2], au2); atomicAdd(&u1[c + 3], au3);
    atomicAdd(&s[c + 0], as0);  atomicAdd(&s[c + 1], as1);
    atomicAdd(&s[c + 2], as2);  atomicAdd(&s[c + 3], as3);
  } else {
    size_t i = (size_t)(b - 255) * 256 + t;
    const size_t n4 = NNOC / 4;
    if (i >= n4) return;
    float4 sv;
    if (nsplit == 16) {
      float4 v[16];
#pragma unroll
      for (int pp = 0; pp < 16; pp++) v[pp] = Kp4[(size_t)pp * n4 + i];
      sv = v[0];
#pragma unroll
      for (int pp = 1; pp < 16; pp++) {
        sv.x += v[pp].x; sv.y += v[pp].y; sv.z += v[pp].z; sv.w += v[pp].w;
      }
    } else if (nsplit == 8) {
      float4 v[8];
#pragma unroll
      for (int pp = 0; pp < 8; pp++) v[pp] = Kp4[(size_t)pp * n4 + i];
      sv = v[0];
#pragma unroll
      for (int pp = 1; pp < 8; pp++) {
        sv.x += v[pp].x; sv.y += v[pp].y; sv.z += v[pp].z; sv.w += v[pp].w;
      }
    } else {
      sv = Kp4[i];
      for (int pp = 1; pp < nsplit; pp++) {
        float4 v = Kp4[(size_t)pp * n4 + i];
        sv.x += v.x; sv.y += v.y; sv.z += v.z; sv.w += v.w;
      }
    }
    Kf4[i] = sv;
  }
}

// ============ kernel D: p = U@(lmbd*u1), q = U@(lmbd*s), one wave per row ============
__global__ __launch_bounds__(256) void uv_kernel(const float4* __restrict__ U4, const float4* __restrict__ L4,
                                                 const double2* __restrict__ u1d, const double2* __restrict__ sd,
                                                 double* __restrict__ p, double* __restrict__ q) {
  const int t = threadIdx.x;
  const int wave = t >> 6, lane = t & 63;
  const int r = blockIdx.x * 4 + wave;
  if (r >= NN) return;
  const float4* Ur = U4 + (size_t)r * NV;
  double ap = 0.0, aq = 0.0;
  for (int c4 = lane; c4 < NV; c4 += 64) {
    float4 u = Ur[c4];
    float4 lm = L4[c4];
    double2 ua = u1d[c4 * 2], ub = u1d[c4 * 2 + 1];
    double2 sa = sd[c4 * 2],  sb = sd[c4 * 2 + 1];
    ap = fma((double)u.x, (double)lm.x * ua.x, ap);
    ap = fma((double)u.y, (double)lm.y * ua.y, ap);
    ap = fma((double)u.z, (double)lm.z * ub.x, ap);
    ap = fma((double)u.w, (double)lm.w * ub.y, ap);
    aq = fma((double)u.x, (double)lm.x * sa.x, aq);
    aq = fma((double)u.y, (double)lm.y * sa.y, aq);
    aq = fma((double)u.z, (double)lm.z * sb.x, aq);
    aq = fma((double)u.w, (double)lm.w * sb.y, aq);
  }
  for (int o = 32; o; o >>= 1) { ap += __shfl_down(ap, o, 64); aq += __shfl_down(aq, o, 64); }
  if (lane == 0) { p[r] = ap; q[r] = aq; }
}

// ============ kernel E: SINGLE-scan masked softmax + in-LDS filter + deep-ILP gather ============
// Scan once: candidates with av > wave_running_max - 21 (superset of final keep), exact max tracked.
// Filter in LDS vs exact max (chunked, in-place): w = exp(av - m), keep av > m-21.
// Gather: H[i] = sum_keep w_j * K[j] / sumw — 8 candidates / 16 loads in flight per lane.
__global__ __launch_bounds__(256) void softmaxH_fused(const unsigned* __restrict__ bm,
                                                      const double* __restrict__ p, const double* __restrict__ q,
                                                      const double* __restrict__ k2,
                                                      const float* __restrict__ K, float* __restrict__ H) {
  __shared__ float vf[NN];
  __shared__ short js[NN];
  __shared__ float hpart[4][128];
  __shared__ unsigned bmr[NW];
  __shared__ double redd[4];
  __shared__ float redf[4];
  __shared__ int wcnt[4];
  __shared__ int cntS;

  const int i = blockIdx.x;
  const int t = threadIdx.x;
  const int wv = t >> 6, lane = t & 63;
  const double pi = p[i], qi = q[i];
  const unsigned long long ltmask = (1ull << lane) - 1ull;

  if (t < NW) bmr[t] = bm[(size_t)i * NW + t];
  if (t == 0) cntS = 0;
  __syncthreads();

  // ---- single scan: online superset-compaction + exact max ----
  double mw = -1e300;   // per-wave running max (lower bound of final m at all times)
  for (int j = t; j < NN; j += 256) {
    bool nb = (bmr[j >> 5] >> (j & 31)) & 1u;
    double av = nb ? fabs(fma(qi, k2[j], pi)) : -1e300;
    bool keep = nb && (av > mw - 21.0);     // superset of final keep (mw <= m)
    double amax = av;
    for (int o = 32; o; o >>= 1) amax = fmax(amax, __shfl_xor(amax, o, 64));
    unsigned long long mask = __ballot(keep);
    if (mask) {
      int src = __ffsll(mask) - 1;
      int basew = 0;
      if (lane == src) basew = atomicAdd(&cntS, __popcll(mask));
      basew = __shfl(basew, src, 64);
      if (keep) {
        int pos = basew + __popcll(mask & ltmask);
        js[pos] = (short)j;
        vf[pos] = (float)av;
      }
    }
    mw = fmax(mw, amax);
  }
  if (lane == 0) redd[wv] = mw;
  __syncthreads();
  const double m = fmax(fmax(redd[0], redd[1]), fmax(redd[2], redd[3]));
  const int ncand = cntS;

  // ---- in-LDS filter vs exact max + weights (chunked, in-place compaction) ----
  const float fm = (float)m;
  const float thrF = (float)(m - 21.0);     // exp(-21) ~ 7.6e-10 relative mass cut
  float sw = 0.f;
  int outn = 0;
  for (int r0 = 0; r0 < ncand; r0 += 256) {
    int c = r0 + t;
    bool keep = (c < ncand) && (vf[c] > thrF);
    float w = 0.f; short jj = 0;
    if (keep) { w = __expf(vf[c] - fm); jj = js[c]; }
    unsigned long long mask = __ballot(keep);
    int wo = __popcll(mask & ltmask);
    if (lane == 0) wcnt[wv] = __popcll(mask);
    __syncthreads();                        // all reads of this chunk done; wcnt visible
    int c0 = wcnt[0], c1 = wcnt[1], c2 = wcnt[2], c3 = wcnt[3];
    int base = outn + (wv > 0 ? c0 : 0) + (wv > 1 ? c1 : 0) + (wv > 2 ? c2 : 0);
    if (keep) { js[base + wo] = jj; vf[base + wo] = w; sw += w; }
    outn += c0 + c1 + c2 + c3;
    __syncthreads();                        // writes done before wcnt reuse next round
  }
  for (int o = 32; o; o >>= 1) sw += __shfl_xor(sw, o, 64);
  if (lane == 0) redf[wv] = sw;
  __syncthreads();
  const float sumw = (redf[0] + redf[1]) + (redf[2] + redf[3]);
  const int nlist = outn;

  // ---- gather: 8 candidates per batch (stride 4 per wave), 16 global loads in flight ----
  const int ch = t & 63, g = t >> 6;
  float a0 = 0.f, a1 = 0.f;
  int c = g;
  for (; c + 28 < nlist; c += 32) {
    float wr[8]; int jr[8];
#pragma unroll
    for (int u = 0; u < 8; u++) { wr[u] = vf[c + 4 * u]; jr[u] = js[c + 4 * u]; }
    float kl[8], kh[8];
#pragma unroll
    for (int u = 0; u < 8; u++) {
      const float* Kr = K + (size_t)jr[u] * OC;
      kl[u] = Kr[ch]; kh[u] = Kr[64 + ch];
    }
#pragma unroll
    for (int u = 0; u < 8; u++) { a0 = fmaf(wr[u], kl[u], a0); a1 = fmaf(wr[u], kh[u], a1); }
  }
  for (; c < nlist; c += 4) {
    float w = vf[c];
    const float* Kr = K + (size_t)js[c] * OC;
    a0 = fmaf(w, Kr[ch], a0);
    a1 = fmaf(w, Kr[64 + ch], a1);
  }
  hpart[g][ch] = a0;
  hpart[g][64 + ch] = a1;
  __syncthreads();
  if (t < 128) {
    float hv = (hpart[0][t] + hpart[1][t]) + (hpart[2][t] + hpart[3][t]);
    H[(size_t)i * OC + t] = hv / sumw;
  }
}

extern "C" void kernel_launch(void* const* d_in, const int* in_sizes, int n_in,
                              void* d_out, int out_size, void* d_ws, size_t ws_size,
                              hipStream_t stream) {
  const float* X    = (const float*)d_in[0];
  const int*   A    = (const int*)d_in[1];
  const float* U    = (const float*)d_in[2];
  const float* W    = (const float*)d_in[3];
  const float* a1   = (const float*)d_in[4];
  const float* a2   = (const float*)d_in[5];
  const float* lmbd = (const float*)d_in[6];
  float* H = (float*)d_out;

  const size_t wt_bytes  = (size_t)IC * OC * 4;
  const size_t bm_bytes  = (size_t)NN * NW * 4;
  const size_t dbl_bytes = (size_t)(6 * NN + 2 * IC) * 8;

  // split-K cascade by workspace size
  const int splits[5] = {16, 8, 4, 2, 1};
  int nsplit = 1;
  for (int ci = 0; ci < 5; ci++) {
    int ns = splits[ci];
    size_t need = (size_t)(ns > 1 ? ns + 1 : 1) * NNOC * 4 + wt_bytes + dbl_bytes +
                  bm_bytes + 1024;
    if (need <= ws_size) { nsplit = ns; break; }
  }

  char* base = (char*)d_ws;
  float* Kp = (float*)base;
  float* Kf = (nsplit > 1) ? (float*)(base + (size_t)nsplit * NNOC * 4) : Kp;
  size_t off = (size_t)(nsplit > 1 ? nsplit + 1 : 1) * NNOC * 4;
  float* Wt = (float*)(base + off);            off += wt_bytes;
  double* dbl = (double*)(base + off);         off += dbl_bytes;
  double* k1  = dbl;
  double* k2  = k1 + NN;
  double* u1  = k2 + NN;
  double* sC  = u1 + NN;
  double* p   = sC + NN;
  double* q   = p  + NN;
  double* w1  = q  + NN;
  double* w2  = w1 + IC;
  unsigned* bm = (unsigned*)(base + off);      off += bm_bytes;

  const int chunk = (IC + nsplit - 1) / nsplit;
  const int nmerge = (int)((NNOC / 4 + 255) / 256);   // 339

  // A: bitmap+zero | transposeW | wvec        (900 + 180 + 6 = 1086 blocks)
  prep<<<1086, 256, 0, stream>>>(A, bm, u1, 2 * NN, W, Wt, a1, a2, w1, w2);
  // B: xw | gemmK                              (677 + 85*nsplit blocks)
  xw_gemm<<<677 + 85 * nsplit, 256, 0, stream>>>(X, w1, w2, k1, k2, Wt, Kp, chunk);
  // C: ut_reduce | mergeK                      (255 [+339] blocks of 256)
  mid<<<255 + (nsplit > 1 ? nmerge : 0), 256, 0, stream>>>((const float4*)U, k1, u1, sC,
                                                           (const float4*)Kp, (float4*)Kf, nsplit);
  // D: uv
  uv_kernel<<<NN / 4, 256, 0, stream>>>((const float4*)U, (const float4*)lmbd,
                                        (const double2*)u1, (const double2*)sC, p, q);
  // E: single-scan softmax + deep-ILP gather
  softmaxH_fused<<<NN, 256, 0, stream>>>(bm, p, q, k2, Kf, H);
}

// Round 7
// 202.194 us; speedup vs baseline: 2.1662x; 1.0542x over previous
//
#include <hip/hip_runtime.h>
#include <math.h>

#define NN 2708
#define IC 1433
#define OC 128
#define NV (NN / 4)          // 677 float4/int4 per row (exact)
#define NNOC ((size_t)NN * OC)
#define NW 85                // ceil(NN/32) bitmap words per row

// ============ kernel A: prep2 = { transposeW | wvec | zero u1/sC } (208 blocks) ============
__global__ __launch_bounds__(256) void prep2(const float* __restrict__ W, float* __restrict__ Wt,
                                             const float* __restrict__ a1, const float* __restrict__ a2,
                                             double* __restrict__ w1, double* __restrict__ w2,
                                             double* __restrict__ zd, int nzd) {
  __shared__ float tile[32][33];
  const int b = blockIdx.x, t = threadIdx.x;
  if (b < 180) {
    const int k0 = (b % 45) * 32, o0 = (b / 45) * 32;
#pragma unroll
    for (int it = 0; it < 4; it++) {
      int ro = (t >> 5) + it * 8;
      int k  = k0 + (t & 31);
      tile[ro][t & 31] = (k < IC) ? W[(size_t)(o0 + ro) * IC + k] : 0.f;
    }
    __syncthreads();
#pragma unroll
    for (int it = 0; it < 4; it++) {
      int rk = (t >> 5) + it * 8;
      int k  = k0 + rk;
      if (k < IC) Wt[(size_t)k * OC + o0 + (t & 31)] = tile[t & 31][rk];
    }
  } else if (b < 186) {
    float* a1s = &tile[0][0];
    float* a2s = a1s + 128;
    if (t < 128) { a1s[t] = a1[t]; a2s[t] = a2[t]; }
    __syncthreads();
    int c = (b - 180) * 256 + t;
    if (c < IC) {
      const float* Wc = W + c;
      double s1 = 0.0, s2 = 0.0;
#pragma unroll 4
      for (int o = 0; o < OC; o++) {
        double w = (double)Wc[(size_t)o * IC];
        s1 = fma(w, (double)a1s[o], s1);
        s2 = fma(w, (double)a2s[o], s2);
      }
      w1[c] = s1; w2[c] = s2;
    }
  } else {
    int gid = (b - 186) * 256 + t;
    if (gid < nzd) zd[gid] = 0.0;
  }
}

// ============ kernel B: { xw | gemmK | bitmapA } ============
// blocks [0,677): k1 = X@w1, k2 = X@w2 (fp64, LDS-staged vectors), one wave per row
// blocks [677, 677+85*nsplit): K partials = X @ Wt over k-chunk (fp32)
// blocks [677+85*nsplit, +900): bitmap of A (independent; overlaps with gemm compute)
__global__ __launch_bounds__(256) void xw_gemm(const float* __restrict__ X,
                                               const double* __restrict__ w1, const double* __restrict__ w2,
                                               double* __restrict__ k1, double* __restrict__ k2,
                                               const float* __restrict__ Wt, float* __restrict__ Kp,
                                               const int* __restrict__ A, unsigned* __restrict__ bm,
                                               int chunk, int nsplit) {
  __shared__ __align__(16) char smem[23040];   // max(2*IC*8=22928, 32*36*4+32*132*4=21504)
  const int b = blockIdx.x, t = threadIdx.x;
  const int ngm = 85 * nsplit;
  if (b < NN / 4) {
    double* w1s = (double*)smem;
    double* w2s = w1s + IC;
    for (int c = t; c < IC; c += 256) { w1s[c] = w1[c]; w2s[c] = w2[c]; }
    __syncthreads();
    const int wave = t >> 6, lane = t & 63;
    const int i = b * 4 + wave;
    const float* Xi = X + (size_t)i * IC;
    double s1 = 0.0, s2 = 0.0;
    for (int c = lane; c < IC; c += 64) {
      double x = (double)Xi[c];
      s1 = fma(x, w1s[c], s1);
      s2 = fma(x, w2s[c], s2);
    }
    for (int o = 32; o; o >>= 1) { s1 += __shfl_down(s1, o, 64); s2 += __shfl_down(s2, o, 64); }
    if (lane == 0) { k1[i] = s1; k2[i] = s2; }
  } else if (b < NN / 4 + ngm) {
    float (*Xs)[36]  = (float (*)[36])smem;
    float (*Ws)[132] = (float (*)[132])(smem + 32 * 36 * 4);
    const int bb = b - NN / 4;
    const int bx = bb % 85, by = bb / 85;
    const int rb = bx * 32;
    const int ks = by * chunk;
    const int ke = min(IC, ks + chunk);
    float* __restrict__ Ko = Kp + (size_t)by * NNOC;
    const int row0 = (t >> 5) * 4;
    const int col4 = (t & 31) * 4;
    float acc[4][4];
#pragma unroll
    for (int r = 0; r < 4; r++)
#pragma unroll
      for (int c = 0; c < 4; c++) acc[r][c] = 0.f;

    for (int kb = ks; kb < ke; kb += 32) {
#pragma unroll
      for (int it = 0; it < 4; it++) {
        int idx = t + it * 256;
        int r = idx >> 5, c = idx & 31;
        int gr = rb + r, gc = kb + c;
        Xs[r][c] = (gr < NN && gc < ke) ? X[(size_t)gr * IC + gc] : 0.f;
      }
#pragma unroll
      for (int it = 0; it < 4; it++) {
        int idx4 = t + it * 256;
        int k = idx4 >> 5, cg = (idx4 & 31) * 4;
        int gk = kb + k;
        float4 v = make_float4(0.f, 0.f, 0.f, 0.f);
        if (gk < ke) v = *reinterpret_cast<const float4*>(&Wt[(size_t)gk * OC + cg]);
        *reinterpret_cast<float4*>(&Ws[k][cg]) = v;
      }
      __syncthreads();
#pragma unroll
      for (int g = 0; g < 8; g++) {
        float xr[4][4];
#pragma unroll
        for (int r = 0; r < 4; r++)
          *reinterpret_cast<float4*>(xr[r]) = *reinterpret_cast<const float4*>(&Xs[row0 + r][g * 4]);
#pragma unroll
        for (int j = 0; j < 4; j++) {
          const float4 w4 = *reinterpret_cast<const float4*>(&Ws[g * 4 + j][col4]);
#pragma unroll
          for (int r = 0; r < 4; r++) {
            acc[r][0] = fmaf(xr[r][j], w4.x, acc[r][0]);
            acc[r][1] = fmaf(xr[r][j], w4.y, acc[r][1]);
            acc[r][2] = fmaf(xr[r][j], w4.z, acc[r][2]);
            acc[r][3] = fmaf(xr[r][j], w4.w, acc[r][3]);
          }
        }
      }
      __syncthreads();
    }
#pragma unroll
    for (int r = 0; r < 4; r++) {
      int gr = rb + row0 + r;
      if (gr < NN) {
        float4 v = make_float4(acc[r][0], acc[r][1], acc[r][2], acc[r][3]);
        *reinterpret_cast<float4*>(&Ko[(size_t)gr * OC + col4]) = v;
      }
    }
  } else {
    const int bb = b - NN / 4 - ngm;
    int gid = bb * 256 + t;
    const int total = NN * NW;
    if (gid >= total) return;
    int i = gid / NW, w = gid - i * NW;
    const int* Ar = A + (size_t)i * NN + w * 32;
    unsigned word = 0;
    if (w < NW - 1) {
      const int4* a4 = (const int4*)Ar;
#pragma unroll
      for (int u = 0; u < 8; u++) {
        int4 a = a4[u];
        word |= (a.x != 0 ? 1u : 0u) << (4 * u);
        word |= (a.y != 0 ? 1u : 0u) << (4 * u + 1);
        word |= (a.z != 0 ? 1u : 0u) << (4 * u + 2);
        word |= (a.w != 0 ? 1u : 0u) << (4 * u + 3);
      }
    } else {
      const int nbits = NN - w * 32;
      for (int bb2 = 0; bb2 < nbits; bb2++) word |= (Ar[bb2] != 0 ? 1u : 0u) << bb2;
    }
    bm[(size_t)i * NW + w] = word;
  }
}

// ============ kernel C: { ut_reduce | mergeK }, 256-thread blocks ============
// blocks [0,255): u1 = U^T@k1, s = U^T@1 (fp64, atomics); slab=b/3 (32 rows), chunk=b%3 (256 cols4)
// blocks [255, 255+339) (only if nsplit>1): merge split-K partials, 16 loads in flight
__global__ __launch_bounds__(256) void mid(const float4* __restrict__ U4, const double* __restrict__ k1,
                                           double* __restrict__ u1, double* __restrict__ s,
                                           const float4* __restrict__ Kp4, float4* __restrict__ Kf4,
                                           int nsplit) {
  const int b = blockIdx.x, t = threadIdx.x;
  if (b < 255) {
    const int slab = b / 3, chunk = b - slab * 3;
    const int c4 = chunk * 256 + t;
    if (c4 >= NV) return;
    const int r0 = slab * 32;
    const int r1 = min(NN, r0 + 32);
    double au0 = 0, au1_ = 0, au2 = 0, au3 = 0, as0 = 0, as1 = 0, as2 = 0, as3 = 0;
#pragma unroll 4
    for (int r = r0; r < r1; r++) {
      float4 u = U4[(size_t)r * NV + c4];
      double kr = k1[r];
      au0 = fma((double)u.x, kr, au0); au1_ = fma((double)u.y, kr, au1_);
      au2 = fma((double)u.z, kr, au2); au3 = fma((double)u.w, kr, au3);
      as0 += (double)u.x; as1 += (double)u.y; as2 += (double)u.z; as3 += (double)u.w;
    }
    int c = c4 * 4;
    atomicAdd(&u1[c + 0], au0); atomicAdd(&u1[c + 1], au1_);
    atomicAdd(&u1[c + 2], au2); atomicAdd(&u1[c + 3], au3);
    atomicAdd(&s[c + 0], as0);  atomicAdd(&s[c + 1], as1);
    atomicAdd(&s[c + 2], as2);  atomicAdd(&s[c + 3], as3);
  } else {
    size_t i = (size_t)(b - 255) * 256 + t;
    const size_t n4 = NNOC / 4;
    if (i >= n4) return;
    float4 sv;
    if (nsplit == 16) {
      float4 v[16];
#pragma unroll
      for (int pp = 0; pp < 16; pp++) v[pp] = Kp4[(size_t)pp * n4 + i];
      sv = v[0];
#pragma unroll
      for (int pp = 1; pp < 16; pp++) {
        sv.x += v[pp].x; sv.y += v[pp].y; sv.z += v[pp].z; sv.w += v[pp].w;
      }
    } else if (nsplit == 8) {
      float4 v[8];
#pragma unroll
      for (int pp = 0; pp < 8; pp++) v[pp] = Kp4[(size_t)pp * n4 + i];
      sv = v[0];
#pragma unroll
      for (int pp = 1; pp < 8; pp++) {
        sv.x += v[pp].x; sv.y += v[pp].y; sv.z += v[pp].z; sv.w += v[pp].w;
      }
    } else {
      sv = Kp4[i];
      for (int pp = 1; pp < nsplit; pp++) {
        float4 v = Kp4[(size_t)pp * n4 + i];
        sv.x += v.x; sv.y += v.y; sv.z += v.z; sv.w += v.w;
      }
    }
    Kf4[i] = sv;
  }
}

// ============ kernel E: inline uv + two-pass masked softmax + deep-ILP gather ============
// Inline: p_i = U[i]·(λ∘u1), q_i = U[i]·(λ∘s) (fp64, block-reduced; U row is L3-hot from mid).
// Pass 1: exact max over neighbors of |p_i + q_i*k2_j|.
// Pass 2: keep |v| > m-21 (exp(-21) mass cut), wave-aggregated LDS compaction.
// Gather: H[i] = sum_keep w_j * K[j] / sumw — 8 candidates / 16 loads in flight per lane.
__global__ __launch_bounds__(256) void softuvH(const unsigned* __restrict__ bm,
                                               const float4* __restrict__ U4, const float4* __restrict__ L4,
                                               const double2* __restrict__ u1d, const double2* __restrict__ sd,
                                               const double* __restrict__ k2,
                                               const float* __restrict__ K, float* __restrict__ H) {
  __shared__ float vf[NN];
  __shared__ short js[NN];
  __shared__ float hpart[4][128];
  __shared__ unsigned bmr[NW];
  __shared__ double redd[4], redp[4], redq[4];
  __shared__ float redf[4];
  __shared__ int cntS;

  const int i = blockIdx.x;
  const int t = threadIdx.x;
  const int wv = t >> 6, lane = t & 63;
  const unsigned long long ltmask = (1ull << lane) - 1ull;

  if (t < NW) bmr[t] = bm[(size_t)i * NW + t];
  if (t == 0) cntS = 0;

  // ---- inline uv: p_i, q_i ----
  const float4* Ur = U4 + (size_t)i * NV;
  double ap = 0.0, aq = 0.0;
  for (int c4 = t; c4 < NV; c4 += 256) {
    float4 u = Ur[c4];
    float4 lm = L4[c4];
    double2 ua = u1d[c4 * 2], ub = u1d[c4 * 2 + 1];
    double2 sa = sd[c4 * 2],  sb = sd[c4 * 2 + 1];
    ap = fma((double)u.x, (double)lm.x * ua.x, ap);
    ap = fma((double)u.y, (double)lm.y * ua.y, ap);
    ap = fma((double)u.z, (double)lm.z * ub.x, ap);
    ap = fma((double)u.w, (double)lm.w * ub.y, ap);
    aq = fma((double)u.x, (double)lm.x * sa.x, aq);
    aq = fma((double)u.y, (double)lm.y * sa.y, aq);
    aq = fma((double)u.z, (double)lm.z * sb.x, aq);
    aq = fma((double)u.w, (double)lm.w * sb.y, aq);
  }
  for (int o = 32; o; o >>= 1) { ap += __shfl_down(ap, o, 64); aq += __shfl_down(aq, o, 64); }
  if (lane == 0) { redp[wv] = ap; redq[wv] = aq; }
  __syncthreads();
  const double pi = (redp[0] + redp[1]) + (redp[2] + redp[3]);
  const double qi = (redq[0] + redq[1]) + (redq[2] + redq[3]);

  // ---- pass 1: exact neighbor max of |v| ----
  double m = -1e300;
  for (int j = t; j < NN; j += 256) {
    if ((bmr[j >> 5] >> (j & 31)) & 1u) {
      double v = fma(qi, k2[j], pi);
      m = fmax(m, fabs(v));
    }
  }
  for (int o = 32; o; o >>= 1) m = fmax(m, __shfl_xor(m, o, 64));
  if (lane == 0) redd[wv] = m;
  __syncthreads();
  m = fmax(fmax(redd[0], redd[1]), fmax(redd[2], redd[3]));

  // ---- pass 2: weights + wave-aggregated compaction ----
  const double thr = m - 21.0;     // exp(-21) ~ 7.6e-10 relative mass cut
  float sw = 0.f;
  for (int j = t; j < NN; j += 256) {
    bool keep = false;
    double av = 0.0;
    if ((bmr[j >> 5] >> (j & 31)) & 1u) {
      av = fabs(fma(qi, k2[j], pi));
      keep = (av > thr);
    }
    unsigned long long mask = __ballot(keep);
    if (mask) {
      int src = __ffsll(mask) - 1;          // first keeper in wave
      int basew = 0;
      if (lane == src) basew = atomicAdd(&cntS, __popcll(mask));
      basew = __shfl(basew, src, 64);
      if (keep) {
        int pos = basew + __popcll(mask & ltmask);
        float w = __expf((float)(av - m));
        js[pos] = (short)j;
        vf[pos] = w;
        sw += w;
      }
    }
  }
  for (int o = 32; o; o >>= 1) sw += __shfl_xor(sw, o, 64);
  if (lane == 0) redf[wv] = sw;
  __syncthreads();                          // vf/js/cntS/redf all visible
  const float sumw = (redf[0] + redf[1]) + (redf[2] + redf[3]);
  const int nlist = cntS;

  // ---- gather: 8 candidates per batch (stride 4 per wave), 16 global loads in flight ----
  const int ch = t & 63, g = t >> 6;
  float a0 = 0.f, a1 = 0.f;
  int c = g;
  for (; c + 28 < nlist; c += 32) {
    float wr[8]; int jr[8];
#pragma unroll
    for (int u = 0; u < 8; u++) { wr[u] = vf[c + 4 * u]; jr[u] = js[c + 4 * u]; }
    float kl[8], kh[8];
#pragma unroll
    for (int u = 0; u < 8; u++) {
      const float* Kr = K + (size_t)jr[u] * OC;
      kl[u] = Kr[ch]; kh[u] = Kr[64 + ch];
    }
#pragma unroll
    for (int u = 0; u < 8; u++) { a0 = fmaf(wr[u], kl[u], a0); a1 = fmaf(wr[u], kh[u], a1); }
  }
  for (; c < nlist; c += 4) {
    float w = vf[c];
    const float* Kr = K + (size_t)js[c] * OC;
    a0 = fmaf(w, Kr[ch], a0);
    a1 = fmaf(w, Kr[64 + ch], a1);
  }
  hpart[g][ch] = a0;
  hpart[g][64 + ch] = a1;
  __syncthreads();
  if (t < 128) {
    float hv = (hpart[0][t] + hpart[1][t]) + (hpart[2][t] + hpart[3][t]);
    H[(size_t)i * OC + t] = hv / sumw;
  }
}

extern "C" void kernel_launch(void* const* d_in, const int* in_sizes, int n_in,
                              void* d_out, int out_size, void* d_ws, size_t ws_size,
                              hipStream_t stream) {
  const float* X    = (const float*)d_in[0];
  const int*   A    = (const int*)d_in[1];
  const float* U    = (const float*)d_in[2];
  const float* W    = (const float*)d_in[3];
  const float* a1   = (const float*)d_in[4];
  const float* a2   = (const float*)d_in[5];
  const float* lmbd = (const float*)d_in[6];
  float* H = (float*)d_out;

  const size_t wt_bytes  = (size_t)IC * OC * 4;
  const size_t bm_bytes  = (size_t)NN * NW * 4;
  const size_t dbl_bytes = (size_t)(6 * NN + 2 * IC) * 8;

  // split-K cascade by workspace size
  const int splits[5] = {16, 8, 4, 2, 1};
  int nsplit = 1;
  for (int ci = 0; ci < 5; ci++) {
    int ns = splits[ci];
    size_t need = (size_t)(ns > 1 ? ns + 1 : 1) * NNOC * 4 + wt_bytes + dbl_bytes +
                  bm_bytes + 1024;
    if (need <= ws_size) { nsplit = ns; break; }
  }

  char* base = (char*)d_ws;
  float* Kp = (float*)base;
  float* Kf = (nsplit > 1) ? (float*)(base + (size_t)nsplit * NNOC * 4) : Kp;
  size_t off = (size_t)(nsplit > 1 ? nsplit + 1 : 1) * NNOC * 4;
  float* Wt = (float*)(base + off);            off += wt_bytes;
  double* dbl = (double*)(base + off);         off += dbl_bytes;
  double* k1  = dbl;
  double* k2  = k1 + NN;
  double* u1  = k2 + NN;
  double* sC  = u1 + NN;
  double* w1  = sC + NN + 2 * NN;              // (p,q slots retired, kept for layout stability)
  double* w2  = w1 + IC;
  unsigned* bm = (unsigned*)(base + off);      off += bm_bytes;

  const int chunk = (IC + nsplit - 1) / nsplit;
  const int nmerge = (int)((NNOC / 4 + 255) / 256);   // 339

  // A: transposeW | wvec | zero u1/sC        (180 + 6 + 22 = 208 blocks)
  prep2<<<208, 256, 0, stream>>>(W, Wt, a1, a2, w1, w2, u1, 2 * NN);
  // B: xw | gemmK | bitmapA                   (677 + 85*nsplit + 900 blocks)
  xw_gemm<<<677 + 85 * nsplit + 900, 256, 0, stream>>>(X, w1, w2, k1, k2, Wt, Kp, A, bm,
                                                       chunk, nsplit);
  // C: ut_reduce | mergeK                     (255 [+339] blocks of 256)
  mid<<<255 + (nsplit > 1 ? nmerge : 0), 256, 0, stream>>>((const float4*)U, k1, u1, sC,
                                                           (const float4*)Kp, (float4*)Kf, nsplit);
  // E: inline-uv + two-pass softmax + deep-ILP gather
  softuvH<<<NN, 256, 0, stream>>>(bm, (const float4*)U, (const float4*)lmbd,
                                  (const double2*)u1, (const double2*)sC, k2, Kf, H);
}